// Round 12
// baseline (62.638 us; speedup 1.0000x reference)
//
#include <hip/hip_runtime.h>
#include <hip/hip_bf16.h>

#define J_DIM 25
#define T_DIM 120
#define O_DIM 64
#define KPAD  328        // bf16 per ys/Wf row; 656 B = 164 dwords == 4 mod 32 -> 2-way banks
#define XROWS 124        // window rows: row i = x[clamp(i-2)]
#define XPAD  20         // xs row pad (floats)
#define YROWS 128        // 120 valid + 8 garbage (never stored)

typedef __attribute__((ext_vector_type(8))) short bf16x8;
typedef __attribute__((ext_vector_type(4))) float f32x4;

__device__ __forceinline__ unsigned f2bf(float f) {
    union { float f; unsigned u; } v; v.f = f;
    return (v.u + 0x7FFFu + ((v.u >> 16) & 1u)) >> 16;
}
__device__ __forceinline__ unsigned pk2(float lo, float hi) {
    __hip_bfloat162 h = __float22bfloat162_rn(float2{lo, hi});
    unsigned u;
    __builtin_memcpy(&u, &h, 4);
    return u;
}

// ---- W (306x64 f32) -> Wf[o][k], k = 18a + b; b<17: 0.5*W2[a,b]; b==17: W1[a] ----
__global__ void wprep(const float* __restrict__ W, unsigned short* __restrict__ Wf) {
    int i = blockIdx.x * 256 + threadIdx.x;
    if (i >= O_DIM * KPAD) return;
    int o = i / KPAD, k = i % KPAD;
    int a = k / 18, b = k % 18;
    float v = 0.0f;
    if (k < 306) v = (b == 17) ? W[a * O_DIM + o] : 0.5f * W[(17 + 17 * a + b) * O_DIM + o];
    Wf[o * KPAD + k] = (unsigned short)f2bf(v);
}

// ---- main: block = (n, j), 512 threads, all 120 t-rows ----
// launch_bounds 2nd arg kept small: aggressive caps clamp VGPR below need and
// spill (measured R6: 40 VGPR, 200+ MB scratch traffic; R10 same).
__global__ __launch_bounds__(512, 2) void sig_mfma(
    const float* __restrict__ x, const unsigned short* __restrict__ Wf,
    const float* __restrict__ bias, float* __restrict__ out)
{
    __shared__ float xs[XROWS][XPAD];             // 9,920 B
    __shared__ unsigned short ys[YROWS * KPAD];   // 83,968 B  (total 93.9 KB)

    const int tid = threadIdx.x;
    const int j = blockIdx.x % J_DIM;
    const int n = blockIdx.x / J_DIM;
    const int wave = tid >> 6, lane = tid & 63;
    const int l15 = lane & 15, l4 = lane >> 4;

    // ---- stage xs[i][c] = x[n,c,j,clamp(i-2)]  (coalesced runs of 124 dwords) ----
    const float* xbase = x + ((size_t)(n * 16) * J_DIM + j) * T_DIM;
    for (int idx = tid; idx < 16 * XROWS; idx += 512) {
        int c = idx / XROWS, i = idx % XROWS;
        int st = min(max(i - 2, 0), T_DIM - 1);
        xs[i][c] = xbase[(size_t)c * J_DIM * T_DIM + st];
    }
    // zero pad bytes [608,656) of rows 0..119 (608-611 re-written by row-16 store)
    if (tid < 120 * 3) {
        int r = tid / 3, p = tid % 3;
        *(uint4*)((char*)ys + r * 656 + 608 + p * 16) = uint4{0, 0, 0, 0};
    }
    __syncthreads();

    // ---- phase 1: 960 slots (row 0..119, q 0..7); thread does slots tid, tid+512 ----
    // S2[a,b] = sum_w h_w[a] * p_w[b],  h = (-p1, p0-p2, p1-p3, p2-p4, p3+p4)
    #pragma unroll 1
    for (int s = tid; s < 960; s += 512) {
        const int row = s >> 3, q = s & 7;
        const int t = row;
        const int start = max(t - 2, 0), end = min(t + 3, T_DIM);
        const float inv = 1.0f / (float)(end - start - 1);
        float ptv[5];
        #pragma unroll
        for (int w = 0; w < 5; ++w) {
            int pcw = min(max(t - 2 + w, 0), T_DIM - 1);
            ptv[w] = (float)(pcw - start) * inv;
        }
        float pa0[5], pa1[5];
        #pragma unroll
        for (int w = 0; w < 5; ++w) {
            float2 pr = *(const float2*)&xs[row + w][2 * q];
            pa0[w] = pr.x; pa1[w] = pr.y;
        }
        float h0[5], h1[5], ht[5];
        h0[0] = -pa0[1];          h1[0] = -pa1[1];          ht[0] = -ptv[1];
        h0[1] = pa0[0] - pa0[2];  h1[1] = pa1[0] - pa1[2];  ht[1] = ptv[0] - ptv[2];
        h0[2] = pa0[1] - pa0[3];  h1[2] = pa1[1] - pa1[3];  ht[2] = ptv[1] - ptv[3];
        h0[3] = pa0[2] - pa0[4];  h1[3] = pa1[2] - pa1[4];  ht[3] = ptv[2] - ptv[4];
        h0[4] = pa0[3] + pa0[4];  h1[4] = pa1[3] + pa1[4];  ht[4] = ptv[3] + ptv[4];

        unsigned u0[9], u1[9], ut[9];
        float accp0 = 0, accp1 = 0, accpt = 0;
        #pragma unroll
        for (int hb = 0; hb < 2; ++hb) {
            float4 xw[5][2];
            #pragma unroll
            for (int w = 0; w < 5; ++w) {
                const float* rw = &xs[row + w][0];
                xw[w][0] = *(const float4*)(rw + 8 * hb);
                xw[w][1] = *(const float4*)(rw + 8 * hb + 4);
            }
            #pragma unroll
            for (int b8 = 0; b8 < 8; ++b8) {
                float pb[5];
                #pragma unroll
                for (int w = 0; w < 5; ++w) {
                    float4 v = xw[w][b8 >> 2];
                    pb[w] = ((b8 & 3) == 0) ? v.x : ((b8 & 3) == 1) ? v.y
                          : ((b8 & 3) == 2) ? v.z : v.w;
                }
                float a0 = h0[0] * pb[0], a1 = h1[0] * pb[0], at = ht[0] * pb[0];
                #pragma unroll
                for (int w = 1; w < 5; ++w) {
                    a0 = fmaf(h0[w], pb[w], a0);
                    a1 = fmaf(h1[w], pb[w], a1);
                    at = fmaf(ht[w], pb[w], at);
                }
                const int b = hb * 8 + b8;
                if (b & 1) {
                    const int m = b >> 1;
                    u0[m] = pk2(accp0, a0);
                    u1[m] = pk2(accp1, a1);
                    ut[m] = pk2(accpt, at);
                } else { accp0 = a0; accp1 = a1; accpt = at; }
            }
        }
        {   // b = 16 (time column) + S1 slot
            float a0 = h0[0] * ptv[0], a1 = h1[0] * ptv[0], at = ht[0] * ptv[0];
            #pragma unroll
            for (int w = 1; w < 5; ++w) {
                a0 = fmaf(h0[w], ptv[w], a0);
                a1 = fmaf(h1[w], ptv[w], a1);
                at = fmaf(ht[w], ptv[w], at);
            }
            u0[8] = pk2(a0, pa0[4]);
            u1[8] = pk2(a1, pa1[4]);
            ut[8] = pk2(at, ptv[4]);
        }
        char* yr = (char*)ys + row * 656 + 72 * q;   // rows 2q,2q+1: contiguous 72 B
        *(uint2*)(yr +  0) = uint2{u0[0], u0[1]};
        *(uint2*)(yr +  8) = uint2{u0[2], u0[3]};
        *(uint2*)(yr + 16) = uint2{u0[4], u0[5]};
        *(uint2*)(yr + 24) = uint2{u0[6], u0[7]};
        *(uint2*)(yr + 32) = uint2{u0[8], u1[0]};
        *(uint2*)(yr + 40) = uint2{u1[1], u1[2]};
        *(uint2*)(yr + 48) = uint2{u1[3], u1[4]};
        *(uint2*)(yr + 56) = uint2{u1[5], u1[6]};
        *(uint2*)(yr + 64) = uint2{u1[7], u1[8]};
        if (q == 0) {                                // row a=16 at bytes [576,612)
            char* yr16 = (char*)ys + row * 656 + 576;
            *(uint2*)(yr16 +  0) = uint2{ut[0], ut[1]};
            *(uint2*)(yr16 +  8) = uint2{ut[2], ut[3]};
            *(uint2*)(yr16 + 16) = uint2{ut[4], ut[5]};
            *(uint2*)(yr16 + 24) = uint2{ut[6], ut[7]};
            *(unsigned*)(yr16 + 32) = ut[8];
        }
    }
    __syncthreads();

    // ---- phase 2: wave = (o-column cc, M-half mh); B-frags loaded once, 4 M-tiles ----
    {
        const int cc = wave & 3, mh = wave >> 2;
        const float bv = bias[cc * 16 + l15];
        const unsigned short* Bb = Wf + (size_t)(cc * 16 + l15) * KPAD + l4 * 8;
        bf16x8 bf[10];
        #pragma unroll
        for (int kk = 0; kk < 10; ++kk)
            bf[kk] = *(const bf16x8*)(Bb + kk * 32);
        #pragma unroll
        for (int mi = 0; mi < 4; ++mi) {
            const int m = mh * 4 + mi;
            const char* Ab = (const char*)ys + (m * 16 + l15) * 656 + l4 * 16;
            f32x4 acc = f32x4{bv, bv, bv, bv};
            #pragma unroll
            for (int kk = 0; kk < 10; ++kk) {
                bf16x8 af = *(const bf16x8*)(Ab + kk * 64);
                acc = __builtin_amdgcn_mfma_f32_16x16x32_bf16(af, bf[kk], acc, 0, 0, 0);
            }
            const int tg = m * 16 + l4 * 4;          // row = l4*4 + reg -> t
            if (tg < T_DIM) {
                float* op = out + ((size_t)(n * O_DIM + cc * 16 + l15) * J_DIM + j) * T_DIM + tg;
                *(f32x4*)op = acc;
            }
        }
    }
}

extern "C" void kernel_launch(void* const* d_in, const int* in_sizes, int n_in,
                              void* d_out, int out_size, void* d_ws, size_t ws_size,
                              hipStream_t stream) {
    const float* x = (const float*)d_in[0];
    const float* W = (const float*)d_in[1];
    const float* b = (const float*)d_in[2];
    float* out = (float*)d_out;
    unsigned short* Wf = (unsigned short*)d_ws;   // 64*328*2 = 41,984 B

    wprep<<<(O_DIM * KPAD + 255) / 256, 256, 0, stream>>>(W, Wf);
    sig_mfma<<<64 * J_DIM, 512, 0, stream>>>(x, Wf, b, out);
}